// Round 1
// baseline (10872.881 us; speedup 1.0000x reference)
//
#include <hip/hip_runtime.h>

// LSTM B=64 T=512 I=512 H=1024 — round 8.
// Round-7 diagnosis: step time 6.2us matches 64 MB/step of sc0sc1 h-loads
// served by the LLC at ~10 TB/s (32.7 GB/dispatch, invisible in FETCH_SIZE
// which is HBM-only). Kernel is LLC-BW-bound on redundant coherent reads:
// every wave re-fetches its h slice from the MALL, 2x mt-redundancy per block.
// Fix: consumer h loads become PLAIN CACHED loads guarded by an agent-scope
// acquire fence (s_waitcnt + buffer_inv sc1 => L1 + XCD-L2 invalidate) issued
// after the counter poll succeeds. h lines then fill each XCD L2 once per step
// (~2 MB/step LLC traffic, 32x less) and the 64 MB/step of reads come from
// per-XCD L2 (34.5 TB/s agg) + L1 (absorbs mt-pair redundancy).
// Safety: poll stays a relaxed agent-scope (sc1) load — cached polling would
// spin on a stale line forever. Producer path unchanged (write-through u16
// stores + vmcnt ack + relaxed add). Staleness: each consumer fences AFTER
// observing the counter; D=2 skew argument (publish of h_{t+2} is
// data-dependent on every wave's h_t loads via red+syncthreads) guarantees no
// reader of buffer P can be in flight once P is rewritten, so post-fence fills
// always pull fresh LLC data.

typedef short bf16x8 __attribute__((ext_vector_type(8)));
typedef float f32x4  __attribute__((ext_vector_type(4)));

#define BB 64
#define TT 512
#define II 512
#define HH 1024

#define NBLK 256
#define NTHR 512

// ws layout (bytes)
#define WS_CNT_OFF   0                       // 8 counters, 256B apart (memset 8K)
#define WS_HPAKH_OFF 8192                    // u16 [2][HH/8][BB][8] = 256 KB
#define WS_HPAKL_OFF (8192 + 262144)
#define WS_XPAKH_OFF (1 << 20)               // u16 [TT][II/8][BB][8] = 32 MB
#define WS_XPAKL_OFF ((1 << 20) + (32u << 20))

#define HBUF_STRIDE 65536                    // u16 per h buffer
#define XT_STRIDE   32768                    // u16 per timestep of x

__device__ __forceinline__ int atomic_add_rlx(int* p) {
    return __hip_atomic_fetch_add(p, 1, __ATOMIC_RELAXED, __HIP_MEMORY_SCOPE_AGENT);
}
__device__ __forceinline__ int load_rlx(const int* p) {
    return __hip_atomic_load(p, __ATOMIC_RELAXED, __HIP_MEMORY_SCOPE_AGENT);
}
__device__ __forceinline__ void store_wt_u16(unsigned short* p, unsigned short v) {
    __hip_atomic_store(p, v, __ATOMIC_RELAXED, __HIP_MEMORY_SCOPE_AGENT);
}

__device__ __forceinline__ float fast_sigmoid(float x) {
    return 1.0f / (1.0f + __expf(-x));
}
__device__ __forceinline__ float fast_tanh(float x) {
    x = fminf(15.0f, fmaxf(-15.0f, x));
    const float e = __expf(2.0f * x);
    return (e - 1.0f) / (e + 1.0f);
}

// fp32 -> bf16 hi + bf16 lo-of-residual (RNE both)
__device__ __forceinline__ void split_bf16(float x, unsigned& hi, unsigned& lo)
{
    unsigned b = __float_as_uint(x);
    hi = (b + 0x7fffu + ((b >> 16) & 1u)) >> 16;
    float r = x - __uint_as_float(hi << 16);
    unsigned bl = __float_as_uint(r);
    lo = (bl + 0x7fffu + ((bl >> 16) & 1u)) >> 16;
}

#define MFMA(A, B, C) __builtin_amdgcn_mfma_f32_16x16x32_bf16((A), (B), (C), 0, 0, 0)

// x -> split planes, layout [t][k>>3][b][k&7] u16 per plane
__global__ void __launch_bounds__(256)
transpose_pack_x(const float* __restrict__ x,
                 unsigned short* __restrict__ xH, unsigned short* __restrict__ xL)
{
    __shared__ float tile[64][65];
    const int t   = (int)blockIdx.x;
    const int tid = (int)threadIdx.x;
    const int li  = tid & 63;
    const int w4  = tid >> 6;

    for (int kc = 0; kc < II; kc += 64) {
#pragma unroll
        for (int r = 0; r < 16; ++r) {
            const int b = w4 * 16 + r;
            tile[b][li] = x[((size_t)b * TT + t) * II + kc + li];
        }
        __syncthreads();
#pragma unroll
        for (int half = 0; half < 2; ++half) {
            const int u  = tid + half * 256;      // u = k8*64 + b
            const int k8 = u >> 6, b = u & 63;
            unsigned short oh[8], ol[8];
#pragma unroll
            for (int e = 0; e < 8; ++e) {
                unsigned hi, lo;
                split_bf16(tile[b][k8 * 8 + e], hi, lo);
                oh[e] = (unsigned short)hi;
                ol[e] = (unsigned short)lo;
            }
            const size_t idx = (size_t)t * XT_STRIDE + ((kc >> 3) + k8) * 512 + b * 8;
            *(uint4*)(xH + idx) = *(const uint4*)oh;
            *(uint4*)(xL + idx) = *(const uint4*)ol;
        }
        __syncthreads();
    }
}

__global__ void __launch_bounds__(NTHR, 2)   // <=256 VGPR, 1 block/CU
lstm_mfma(const unsigned short* __restrict__ xH,
          const unsigned short* __restrict__ xL,
          const int*   __restrict__ lens,
          const float* __restrict__ Wih,     // [4H][I]
          const float* __restrict__ Whh,     // [4H][H]
          const float* __restrict__ bih,
          const float* __restrict__ bhh,
          unsigned short* __restrict__ hH,   // [2][H/8][B][8]
          unsigned short* __restrict__ hL,
          int*   __restrict__ cnts,          // 8 counters, 64-int stride
          float* __restrict__ out)           // [B][H]
{
    __shared__ float red[2][2][3][2][16][17];  // [parity][mt][src-1][nt][bsub][pad17] ~26KB

    const int tid  = (int)threadIdx.x;
    const int l    = tid & 63;
    const int p    = __builtin_amdgcn_readfirstlane(tid >> 6);  // wave 0..7
    const int kh   = p & 3;                  // k-split 0..3
    const int mt   = p >> 2;                 // m-tile 0..1
    const int bsub = l & 15;
    const int q    = l >> 4;                 // quad

    const int jt = (int)blockIdx.x >> 1;
    const int bh = (int)blockIdx.x & 1;
    const int j0 = jt * 8;

    const int bofs[2] = {(bh * 32 + bsub) * 8, (bh * 32 + 16 + bsub) * 8};

    int*       prodc = cnts + (bh * 4 + (jt >> 5)) * 64;   // my quarter's counter
    const int* consc = cnts + (bh * 4 + kh) * 64;          // quarter I consume

    // ---- weight A-fragments -> registers (persist across all t) ----
    const int row = (l & 3) * HH + j0 + mt * 4 + ((l & 15) >> 2);
    bf16x8 whi[12], wlo[12];
#pragma unroll
    for (int kt = 0; kt < 12; ++kt) {
        const int ktg = (kt < 4) ? (4 * kh + kt) : (16 + 8 * kh + (kt - 4));
        const float* src = (ktg < 16)
            ? (Wih + (size_t)row * II + ktg * 32 + q * 8)
            : (Whh + (size_t)row * HH + (ktg - 16) * 32 + q * 8);
        const float4 w0 = *(const float4*)src;
        const float4 w1 = *(const float4*)(src + 4);
        const float wf[8] = {w0.x, w0.y, w0.z, w0.w, w1.x, w1.y, w1.z, w1.w};
#pragma unroll
        for (int e = 0; e < 8; ++e) {
            unsigned hi, lo;
            split_bf16(wf[e], hi, lo);
            whi[kt][e] = (short)hi;
            wlo[kt][e] = (short)lo;
        }
    }

    // ---- per-cell state; init h_0, ack, publish ----
    float bias[4], c[2] = {0.f, 0.f}, lasth[2] = {0.f, 0.f};
    int len[2] = {0, 0};
    const int jcell = j0 + mt * 4 + q;
    const int jlow  = mt * 4 + q;
    const size_t hblk = (size_t)jt * 512;

    if (kh == 0) {
#pragma unroll
        for (int g = 0; g < 4; ++g)
            bias[g] = bih[g * HH + jcell] + bhh[g * HH + jcell];
#pragma unroll
        for (int nt = 0; nt < 2; ++nt) {
            const int b = bh * 32 + nt * 16 + bsub;
            len[nt] = lens[b];
            store_wt_u16(hH + hblk + b * 8 + jlow, 0);   // h_0 = 0, buffer 0
            store_wt_u16(hL + hblk + b * 8 + jlow, 0);
        }
        asm volatile("s_waitcnt vmcnt(0)" ::: "memory");
        if (l == 0) atomic_add_rlx(prodc);               // -> 64 when all ready
    }

    for (int t = 0; t < TT; ++t) {
        // ---- x-part (plain cached b128 loads; independent of h_t) ----
        f32x4 s0[2], s1[2], s2[2];
#pragma unroll
        for (int nt = 0; nt < 2; ++nt)
            s0[nt] = s1[nt] = s2[nt] = (f32x4){0.f, 0.f, 0.f, 0.f};
        {
            const unsigned short* xh = xH + (size_t)t * XT_STRIDE;
            const unsigned short* xl = xL + (size_t)t * XT_STRIDE;
#pragma unroll
            for (int xi = 0; xi < 4; ++xi) {
                const int idx = ((4 * kh + xi) * 4 + q) * 512;
#pragma unroll
                for (int nt = 0; nt < 2; ++nt) {
                    const bf16x8 ahi = *(const bf16x8*)(xh + idx + bofs[nt]);
                    const bf16x8 alo = *(const bf16x8*)(xl + idx + bofs[nt]);
                    s0[nt] = MFMA(whi[xi], ahi, s0[nt]);
                    s1[nt] = MFMA(whi[xi], alo, s1[nt]);
                    s2[nt] = MFMA(wlo[xi], ahi, s2[nt]);
                }
            }
        }

        // ---- wait: my k-quarter of h_t fully published (single dword poll) ----
        {
            const int need = 64 * (t + 1);
            while (load_rlx(consc) < need)
                __builtin_amdgcn_s_sleep(1);
            // acquire: s_waitcnt + buffer_inv sc1 (invalidate L1 + XCD L2) so
            // the plain cached loads below observe the write-through h stores.
            __builtin_amdgcn_fence(__ATOMIC_ACQUIRE, "agent");
        }

        // ---- h-part: plain cached b128 loads (served by XCD L2 / L1) ----
        const unsigned short* hph = hH + (t & 1) * HBUF_STRIDE;
        const unsigned short* hpl = hL + (t & 1) * HBUF_STRIDE;
#pragma unroll
        for (int nt = 0; nt < 2; ++nt) {
#pragma unroll
            for (int hi2 = 0; hi2 < 8; ++hi2) {
                const int idx = (kh * 32 + hi2 * 4 + q) * 512 + bofs[nt];
                const bf16x8 ahi = *(const bf16x8*)(hph + idx);
                const bf16x8 alo = *(const bf16x8*)(hpl + idx);
                s0[nt] = MFMA(whi[4 + hi2], ahi, s0[nt]);
                s1[nt] = MFMA(whi[4 + hi2], alo, s1[nt]);
                s2[nt] = MFMA(wlo[4 + hi2], ahi, s2[nt]);
            }
        }

        // ---- merge streams + single-phase cross-wave reduction ----
        f32x4 acc[2];
#pragma unroll
        for (int nt = 0; nt < 2; ++nt) acc[nt] = s0[nt] + s1[nt] + s2[nt];
        const int pa = t & 1;

        if (kh != 0) {
#pragma unroll
            for (int nt = 0; nt < 2; ++nt)
#pragma unroll
                for (int i = 0; i < 4; ++i)
                    red[pa][mt][kh - 1][nt][bsub][4 * q + i] = acc[nt][i];
        }
        __syncthreads();

        // ---- gate math (kh==0), h store, ack, publish ----
        if (kh == 0) {
            unsigned short* dsth = hH + ((t + 1) & 1) * HBUF_STRIDE + hblk;
            unsigned short* dstl = hL + ((t + 1) & 1) * HBUF_STRIDE + hblk;
#pragma unroll
            for (int nt = 0; nt < 2; ++nt) {
                float g4[4];
#pragma unroll
                for (int i = 0; i < 4; ++i)
                    g4[i] = acc[nt][i] + bias[i]
                          + red[pa][mt][0][nt][bsub][4 * q + i]
                          + red[pa][mt][1][nt][bsub][4 * q + i]
                          + red[pa][mt][2][nt][bsub][4 * q + i];
                const float ig = fast_sigmoid(g4[0]);
                const float fg = fast_sigmoid(g4[1]);
                const float gg = fast_tanh(g4[2]);
                const float og = fast_sigmoid(g4[3]);
                c[nt] = fg * c[nt] + ig * gg;
                const float h = og * fast_tanh(c[nt]);
                unsigned hi, lo;
                split_bf16(h, hi, lo);
                const int b = bh * 32 + nt * 16 + bsub;
                store_wt_u16(dsth + b * 8 + jlow, (unsigned short)hi);
                store_wt_u16(dstl + b * 8 + jlow, (unsigned short)lo);
                if (t == len[nt] - 1) lasth[nt] = h;
            }
            asm volatile("s_waitcnt vmcnt(0)" ::: "memory");  // h stores visible
            if (l == 0) atomic_add_rlx(prodc);                // publish h_{t+1}
        }
    }

    // ---- epilogue ----
    if (kh == 0) {
#pragma unroll
        for (int nt = 0; nt < 2; ++nt) {
            const int b = bh * 32 + nt * 16 + bsub;
            out[(size_t)b * HH + jcell] = lasth[nt];
        }
    }
}

extern "C" void kernel_launch(void* const* d_in, const int* in_sizes, int n_in,
                              void* d_out, int out_size, void* d_ws, size_t ws_size,
                              hipStream_t stream)
{
    const float* seq  = (const float*)d_in[0];
    const int*   lens = (const int*)  d_in[1];
    const float* Wih  = (const float*)d_in[2];
    const float* Whh  = (const float*)d_in[3];
    const float* bih  = (const float*)d_in[4];
    const float* bhh  = (const float*)d_in[5];
    float* out = (float*)d_out;

    char* ws = (char*)d_ws;
    int*            cnts = (int*)           (ws + WS_CNT_OFF);
    unsigned short* hH   = (unsigned short*)(ws + WS_HPAKH_OFF);
    unsigned short* hL   = (unsigned short*)(ws + WS_HPAKL_OFF);
    unsigned short* xH   = (unsigned short*)(ws + WS_XPAKH_OFF);
    unsigned short* xL   = (unsigned short*)(ws + WS_XPAKL_OFF);

    hipMemsetAsync(cnts, 0, 8192, stream);   // monotonic counters start at 0
    transpose_pack_x<<<dim3(TT), dim3(256), 0, stream>>>(seq, xH, xL);
    lstm_mfma<<<dim3(NBLK), dim3(NTHR), 0, stream>>>(xH, xL, lens, Wih, Whh, bih, bhh,
                                                     hH, hL, cnts, out);
}

// Round 3
// 2796.536 us; speedup vs baseline: 3.8880x; 3.8880x over previous
//
#include <hip/hip_runtime.h>

// LSTM B=64 T=512 I=512 H=1024 — round 10.
// Round-9 post-mortem (NaN): issue_coh is asm-volatile; compiler cannot know
// it increments vmcnt, so without an explicit wait the ds_writes stored
// pre-load garbage. Fix: WAITSTG — s_waitcnt vmcnt(0) with all 16 loaded
// u32x4 values flowing THROUGH the asm as "+v" operands (round-7 WAIT16
// pattern), so stores cannot be scheduled before the wait.
// Theory (unchanged): h-load address is mt-independent => mt-pair waves
// fetched identical bytes; 64 MB/step coherent LLC traffic @ ~10 TB/s = the
// whole 6.3us step. Each wave now coherently loads only its mt-half (16 b128
// loads), stages into LDS (u16 [2][128][256] = 128 KB), one syncthreads, both
// waves consume all 8 hi2 fragments from LDS. Coherent traffic 64->32 MB/step.
// LDS: 128K stage + 26K red = 154 KB (<=160 KB/CU, 1 block/CU).
// Ordering: stage(t+1) writes are after end-of-step syncthreads which orders
// after all consumes(t); publish remains data-dependent on every wave's h
// loads via red+syncthreads => D=2 buffer overwrite skew argument holds.

typedef short bf16x8 __attribute__((ext_vector_type(8)));
typedef float f32x4  __attribute__((ext_vector_type(4)));
typedef unsigned u32x4 __attribute__((ext_vector_type(4)));

#define BB 64
#define TT 512
#define II 512
#define HH 1024

#define NBLK 256
#define NTHR 512

// ws layout (bytes)
#define WS_CNT_OFF   0                       // 8 counters, 256B apart (memset 8K)
#define WS_HPAKH_OFF 8192                    // u16 [2][HH/8][BB][8] = 256 KB
#define WS_HPAKL_OFF (8192 + 262144)
#define WS_XPAKH_OFF (1 << 20)               // u16 [TT][II/8][BB][8] = 32 MB
#define WS_XPAKL_OFF ((1 << 20) + (32u << 20))

#define HBUF_STRIDE 65536                    // u16 per h buffer
#define XT_STRIDE   32768                    // u16 per timestep of x

__device__ __forceinline__ int atomic_add_rlx(int* p) {
    return __hip_atomic_fetch_add(p, 1, __ATOMIC_RELAXED, __HIP_MEMORY_SCOPE_AGENT);
}
__device__ __forceinline__ int load_rlx(const int* p) {
    return __hip_atomic_load(p, __ATOMIC_RELAXED, __HIP_MEMORY_SCOPE_AGENT);
}
__device__ __forceinline__ void store_wt_u16(unsigned short* p, unsigned short v) {
    __hip_atomic_store(p, v, __ATOMIC_RELAXED, __HIP_MEMORY_SCOPE_AGENT);
}

__device__ __forceinline__ float fast_sigmoid(float x) {
    return 1.0f / (1.0f + __expf(-x));
}
__device__ __forceinline__ float fast_tanh(float x) {
    x = fminf(15.0f, fmaxf(-15.0f, x));
    const float e = __expf(2.0f * x);
    return (e - 1.0f) / (e + 1.0f);
}

// fp32 -> bf16 hi + bf16 lo-of-residual (RNE both)
__device__ __forceinline__ void split_bf16(float x, unsigned& hi, unsigned& lo)
{
    unsigned b = __float_as_uint(x);
    hi = (b + 0x7fffu + ((b >> 16) & 1u)) >> 16;
    float r = x - __uint_as_float(hi << 16);
    unsigned bl = __float_as_uint(r);
    lo = (bl + 0x7fffu + ((bl >> 16) & 1u)) >> 16;
}

#define MFMA(A, B, C) __builtin_amdgcn_mfma_f32_16x16x32_bf16((A), (B), (C), 0, 0, 0)

// coherent 16B load, issued WITHOUT wait (MUST pair with WAITSTG below)
__device__ __forceinline__ void issue_coh(const unsigned short* p, u32x4& d)
{
    asm volatile("global_load_dwordx4 %0, %1, off sc0 sc1" : "=v"(d) : "v"(p));
}
// drain all VMEM; loaded values flow THROUGH the wait so uses can't be hoisted
#define WAITSTG(FH, FL)                                                       \
    asm volatile("s_waitcnt vmcnt(0)"                                         \
        : "+v"(FH[0][0]), "+v"(FH[0][1]), "+v"(FH[0][2]), "+v"(FH[0][3]),     \
          "+v"(FH[1][0]), "+v"(FH[1][1]), "+v"(FH[1][2]), "+v"(FH[1][3]),     \
          "+v"(FL[0][0]), "+v"(FL[0][1]), "+v"(FL[0][2]), "+v"(FL[0][3]),     \
          "+v"(FL[1][0]), "+v"(FL[1][1]), "+v"(FL[1][2]), "+v"(FL[1][3])      \
        :: "memory")

// x -> split planes, layout [t][k>>3][b][k&7] u16 per plane
__global__ void __launch_bounds__(256)
transpose_pack_x(const float* __restrict__ x,
                 unsigned short* __restrict__ xH, unsigned short* __restrict__ xL)
{
    __shared__ float tile[64][65];
    const int t   = (int)blockIdx.x;
    const int tid = (int)threadIdx.x;
    const int li  = tid & 63;
    const int w4  = tid >> 6;

    for (int kc = 0; kc < II; kc += 64) {
#pragma unroll
        for (int r = 0; r < 16; ++r) {
            const int b = w4 * 16 + r;
            tile[b][li] = x[((size_t)b * TT + t) * II + kc + li];
        }
        __syncthreads();
#pragma unroll
        for (int half = 0; half < 2; ++half) {
            const int u  = tid + half * 256;      // u = k8*64 + b
            const int k8 = u >> 6, b = u & 63;
            unsigned short oh[8], ol[8];
#pragma unroll
            for (int e = 0; e < 8; ++e) {
                unsigned hi, lo;
                split_bf16(tile[b][k8 * 8 + e], hi, lo);
                oh[e] = (unsigned short)hi;
                ol[e] = (unsigned short)lo;
            }
            const size_t idx = (size_t)t * XT_STRIDE + ((kc >> 3) + k8) * 512 + b * 8;
            *(uint4*)(xH + idx) = *(const uint4*)oh;
            *(uint4*)(xL + idx) = *(const uint4*)ol;
        }
        __syncthreads();
    }
}

__global__ void __launch_bounds__(NTHR, 2)   // <=256 VGPR, 1 block/CU
lstm_mfma(const unsigned short* __restrict__ xH,
          const unsigned short* __restrict__ xL,
          const int*   __restrict__ lens,
          const float* __restrict__ Wih,     // [4H][I]
          const float* __restrict__ Whh,     // [4H][H]
          const float* __restrict__ bih,
          const float* __restrict__ bhh,
          unsigned short* __restrict__ hH,   // [2][H/8][B][8]
          unsigned short* __restrict__ hL,
          int*   __restrict__ cnts,          // 8 counters, 64-int stride
          float* __restrict__ out)           // [B][H]
{
    __shared__ float red[2][2][3][2][16][17];     // ~26KB
    __shared__ unsigned short hstg[2][128][256];  // [plane][chunk][b*8] 128KB

    const int tid  = (int)threadIdx.x;
    const int l    = tid & 63;
    const int p    = __builtin_amdgcn_readfirstlane(tid >> 6);  // wave 0..7
    const int kh   = p & 3;                  // k-split 0..3
    const int mt   = p >> 2;                 // m-tile 0..1
    const int bsub = l & 15;
    const int q    = l >> 4;                 // quad

    const int jt = (int)blockIdx.x >> 1;
    const int bh = (int)blockIdx.x & 1;
    const int j0 = jt * 8;

    const int bofs[2] = {(bh * 32 + bsub) * 8, (bh * 32 + 16 + bsub) * 8};

    int*       prodc = cnts + (bh * 4 + (jt >> 5)) * 64;   // my quarter's counter
    const int* consc = cnts + (bh * 4 + kh) * 64;          // quarter I consume

    // ---- weight A-fragments -> registers (persist across all t) ----
    const int row = (l & 3) * HH + j0 + mt * 4 + ((l & 15) >> 2);
    bf16x8 whi[12], wlo[12];
#pragma unroll
    for (int kt = 0; kt < 12; ++kt) {
        const int ktg = (kt < 4) ? (4 * kh + kt) : (16 + 8 * kh + (kt - 4));
        const float* src = (ktg < 16)
            ? (Wih + (size_t)row * II + ktg * 32 + q * 8)
            : (Whh + (size_t)row * HH + (ktg - 16) * 32 + q * 8);
        const float4 w0 = *(const float4*)src;
        const float4 w1 = *(const float4*)(src + 4);
        const float wf[8] = {w0.x, w0.y, w0.z, w0.w, w1.x, w1.y, w1.z, w1.w};
#pragma unroll
        for (int e = 0; e < 8; ++e) {
            unsigned hi, lo;
            split_bf16(wf[e], hi, lo);
            whi[kt][e] = (short)hi;
            wlo[kt][e] = (short)lo;
        }
    }

    // ---- per-cell state; init h_0, ack, publish ----
    float bias[4], c[2] = {0.f, 0.f}, lasth[2] = {0.f, 0.f};
    int len[2] = {0, 0};
    const int jcell = j0 + mt * 4 + q;
    const int jlow  = mt * 4 + q;
    const size_t hblk = (size_t)jt * 512;

    if (kh == 0) {
#pragma unroll
        for (int g = 0; g < 4; ++g)
            bias[g] = bih[g * HH + jcell] + bhh[g * HH + jcell];
#pragma unroll
        for (int nt = 0; nt < 2; ++nt) {
            const int b = bh * 32 + nt * 16 + bsub;
            len[nt] = lens[b];
            store_wt_u16(hH + hblk + b * 8 + jlow, 0);   // h_0 = 0, buffer 0
            store_wt_u16(hL + hblk + b * 8 + jlow, 0);
        }
        asm volatile("s_waitcnt vmcnt(0)" ::: "memory");
        if (l == 0) atomic_add_rlx(prodc);               // -> 64 when all ready
    }

    for (int t = 0; t < TT; ++t) {
        // ---- x-part (plain cached b128 loads; independent of h_t) ----
        f32x4 s0[2], s1[2], s2[2];
#pragma unroll
        for (int nt = 0; nt < 2; ++nt)
            s0[nt] = s1[nt] = s2[nt] = (f32x4){0.f, 0.f, 0.f, 0.f};
        {
            const unsigned short* xh = xH + (size_t)t * XT_STRIDE;
            const unsigned short* xl = xL + (size_t)t * XT_STRIDE;
#pragma unroll
            for (int xi = 0; xi < 4; ++xi) {
                const int idx = ((4 * kh + xi) * 4 + q) * 512;
#pragma unroll
                for (int nt = 0; nt < 2; ++nt) {
                    const bf16x8 ahi = *(const bf16x8*)(xh + idx + bofs[nt]);
                    const bf16x8 alo = *(const bf16x8*)(xl + idx + bofs[nt]);
                    s0[nt] = MFMA(whi[xi], ahi, s0[nt]);
                    s1[nt] = MFMA(whi[xi], alo, s1[nt]);
                    s2[nt] = MFMA(wlo[xi], ahi, s2[nt]);
                }
            }
        }

        // ---- wait: my k-quarter of h_t fully published (single dword poll) ----
        {
            const int need = 64 * (t + 1);
            while (load_rlx(consc) < need)
                __builtin_amdgcn_s_sleep(1);
            asm volatile("" ::: "memory");
        }

        // ---- h-part stage: each wave coherently loads its mt-half only ----
        const unsigned short* hph = hH + (t & 1) * HBUF_STRIDE;
        const unsigned short* hpl = hL + (t & 1) * HBUF_STRIDE;
        {
            u32x4 fh[2][4], fl[2][4];
#pragma unroll
            for (int nt = 0; nt < 2; ++nt)
#pragma unroll
                for (int r = 0; r < 4; ++r) {
                    const int hi2 = mt * 4 + r;
                    const int idx = (kh * 32 + hi2 * 4 + q) * 512 + bofs[nt];
                    issue_coh(hph + idx, fh[nt][r]);
                    issue_coh(hpl + idx, fl[nt][r]);
                }
            WAITSTG(fh, fl);
#pragma unroll
            for (int nt = 0; nt < 2; ++nt)
#pragma unroll
                for (int r = 0; r < 4; ++r) {
                    const int c  = kh * 32 + (mt * 4 + r) * 4 + q;
                    const int lo = (nt * 16 + bsub) * 8;
                    *(u32x4*)&hstg[0][c][lo] = fh[nt][r];
                    *(u32x4*)&hstg[1][c][lo] = fl[nt][r];
                }
        }
        __syncthreads();

        // ---- h-part consume: all 8 hi2 fragments from LDS ----
#pragma unroll
        for (int nt = 0; nt < 2; ++nt) {
#pragma unroll
            for (int hi2 = 0; hi2 < 8; ++hi2) {
                const int c  = kh * 32 + hi2 * 4 + q;
                const int lo = (nt * 16 + bsub) * 8;
                const bf16x8 ahi = *(const bf16x8*)&hstg[0][c][lo];
                const bf16x8 alo = *(const bf16x8*)&hstg[1][c][lo];
                s0[nt] = MFMA(whi[4 + hi2], ahi, s0[nt]);
                s1[nt] = MFMA(whi[4 + hi2], alo, s1[nt]);
                s2[nt] = MFMA(wlo[4 + hi2], ahi, s2[nt]);
            }
        }

        // ---- merge streams + single-phase cross-wave reduction ----
        f32x4 acc[2];
#pragma unroll
        for (int nt = 0; nt < 2; ++nt) acc[nt] = s0[nt] + s1[nt] + s2[nt];
        const int pa = t & 1;

        if (kh != 0) {
#pragma unroll
            for (int nt = 0; nt < 2; ++nt)
#pragma unroll
                for (int i = 0; i < 4; ++i)
                    red[pa][mt][kh - 1][nt][bsub][4 * q + i] = acc[nt][i];
        }
        __syncthreads();

        // ---- gate math (kh==0), h store, ack, publish ----
        if (kh == 0) {
            unsigned short* dsth = hH + ((t + 1) & 1) * HBUF_STRIDE + hblk;
            unsigned short* dstl = hL + ((t + 1) & 1) * HBUF_STRIDE + hblk;
#pragma unroll
            for (int nt = 0; nt < 2; ++nt) {
                float g4[4];
#pragma unroll
                for (int i = 0; i < 4; ++i)
                    g4[i] = acc[nt][i] + bias[i]
                          + red[pa][mt][0][nt][bsub][4 * q + i]
                          + red[pa][mt][1][nt][bsub][4 * q + i]
                          + red[pa][mt][2][nt][bsub][4 * q + i];
                const float ig = fast_sigmoid(g4[0]);
                const float fg = fast_sigmoid(g4[1]);
                const float gg = fast_tanh(g4[2]);
                const float og = fast_sigmoid(g4[3]);
                c[nt] = fg * c[nt] + ig * gg;
                const float h = og * fast_tanh(c[nt]);
                unsigned hi, lo;
                split_bf16(h, hi, lo);
                const int b = bh * 32 + nt * 16 + bsub;
                store_wt_u16(dsth + b * 8 + jlow, (unsigned short)hi);
                store_wt_u16(dstl + b * 8 + jlow, (unsigned short)lo);
                if (t == len[nt] - 1) lasth[nt] = h;
            }
            asm volatile("s_waitcnt vmcnt(0)" ::: "memory");  // h stores visible
            if (l == 0) atomic_add_rlx(prodc);                // publish h_{t+1}
        }
    }

    // ---- epilogue ----
    if (kh == 0) {
#pragma unroll
        for (int nt = 0; nt < 2; ++nt) {
            const int b = bh * 32 + nt * 16 + bsub;
            out[(size_t)b * HH + jcell] = lasth[nt];
        }
    }
}

extern "C" void kernel_launch(void* const* d_in, const int* in_sizes, int n_in,
                              void* d_out, int out_size, void* d_ws, size_t ws_size,
                              hipStream_t stream)
{
    const float* seq  = (const float*)d_in[0];
    const int*   lens = (const int*)  d_in[1];
    const float* Wih  = (const float*)d_in[2];
    const float* Whh  = (const float*)d_in[3];
    const float* bih  = (const float*)d_in[4];
    const float* bhh  = (const float*)d_in[5];
    float* out = (float*)d_out;

    char* ws = (char*)d_ws;
    int*            cnts = (int*)           (ws + WS_CNT_OFF);
    unsigned short* hH   = (unsigned short*)(ws + WS_HPAKH_OFF);
    unsigned short* hL   = (unsigned short*)(ws + WS_HPAKL_OFF);
    unsigned short* xH   = (unsigned short*)(ws + WS_XPAKH_OFF);
    unsigned short* xL   = (unsigned short*)(ws + WS_XPAKL_OFF);

    hipMemsetAsync(cnts, 0, 8192, stream);   // monotonic counters start at 0
    transpose_pack_x<<<dim3(TT), dim3(256), 0, stream>>>(seq, xH, xL);
    lstm_mfma<<<dim3(NBLK), dim3(NTHR), 0, stream>>>(xH, xL, lens, Wih, Whh, bih, bhh,
                                                     hH, hL, cnts, out);
}

// Round 5
// 2752.260 us; speedup vs baseline: 3.9505x; 1.0161x over previous
//
#include <hip/hip_runtime.h>

// LSTM B=64 T=512 I=512 H=1024 — round 12 (= round 11 resubmitted; the
// round-11 bench died to an infra "container failed twice" with no data).
// Round-10 post-mortem: traffic halving gained only 0.72us/step => h path is
// latency/serial-chain bound with contention-inflated LLC RTTs, not BW-bound.
// Main suspect: 2048 waves polling 8 counter lines with sc0sc1 reads, queuing
// at the LLC slices and inflating all coherent RTTs (polls share the path
// with h loads). Change under test: SINGLE POLLER PER BLOCK — wave p==7 polls
// the 4 quarter counters (lane l polls counter l&3; divergent while = max
// over quarters), then broadcasts step-ready via an LDS flag; other 7 waves
// spin on LDS only. Semantically equivalent (stage syncthreads already forced
// max-over-quarters before any consume), but 8x fewer LLC poll transactions.
// Ordering: producer stores->vmcnt0->atomic; poller sees counter>=need; flag
// write data-depends on that; consumers load only after flag => every link a
// completed RTT => loads serviced after stores landed. Flag monotone t+1,
// init'd behind a barrier; stage barrier prevents poller lapping readers.

typedef short bf16x8 __attribute__((ext_vector_type(8)));
typedef float f32x4  __attribute__((ext_vector_type(4)));
typedef unsigned u32x4 __attribute__((ext_vector_type(4)));

#define BB 64
#define TT 512
#define II 512
#define HH 1024

#define NBLK 256
#define NTHR 512

// ws layout (bytes)
#define WS_CNT_OFF   0                       // 8 counters, 256B apart (memset 8K)
#define WS_HPAKH_OFF 8192                    // u16 [2][HH/8][BB][8] = 256 KB
#define WS_HPAKL_OFF (8192 + 262144)
#define WS_XPAKH_OFF (1 << 20)               // u16 [TT][II/8][BB][8] = 32 MB
#define WS_XPAKL_OFF ((1 << 20) + (32u << 20))

#define HBUF_STRIDE 65536                    // u16 per h buffer
#define XT_STRIDE   32768                    // u16 per timestep of x

__device__ __forceinline__ int atomic_add_rlx(int* p) {
    return __hip_atomic_fetch_add(p, 1, __ATOMIC_RELAXED, __HIP_MEMORY_SCOPE_AGENT);
}
__device__ __forceinline__ int load_rlx(const int* p) {
    return __hip_atomic_load(p, __ATOMIC_RELAXED, __HIP_MEMORY_SCOPE_AGENT);
}
__device__ __forceinline__ void store_wt_u16(unsigned short* p, unsigned short v) {
    __hip_atomic_store(p, v, __ATOMIC_RELAXED, __HIP_MEMORY_SCOPE_AGENT);
}

__device__ __forceinline__ float fast_sigmoid(float x) {
    return 1.0f / (1.0f + __expf(-x));
}
__device__ __forceinline__ float fast_tanh(float x) {
    x = fminf(15.0f, fmaxf(-15.0f, x));
    const float e = __expf(2.0f * x);
    return (e - 1.0f) / (e + 1.0f);
}

// fp32 -> bf16 hi + bf16 lo-of-residual (RNE both)
__device__ __forceinline__ void split_bf16(float x, unsigned& hi, unsigned& lo)
{
    unsigned b = __float_as_uint(x);
    hi = (b + 0x7fffu + ((b >> 16) & 1u)) >> 16;
    float r = x - __uint_as_float(hi << 16);
    unsigned bl = __float_as_uint(r);
    lo = (bl + 0x7fffu + ((bl >> 16) & 1u)) >> 16;
}

#define MFMA(A, B, C) __builtin_amdgcn_mfma_f32_16x16x32_bf16((A), (B), (C), 0, 0, 0)

// coherent 16B load, issued WITHOUT wait (MUST pair with WAITSTG below)
__device__ __forceinline__ void issue_coh(const unsigned short* p, u32x4& d)
{
    asm volatile("global_load_dwordx4 %0, %1, off sc0 sc1" : "=v"(d) : "v"(p));
}
// drain all VMEM; loaded values flow THROUGH the wait so uses can't be hoisted
#define WAITSTG(FH, FL)                                                       \
    asm volatile("s_waitcnt vmcnt(0)"                                         \
        : "+v"(FH[0][0]), "+v"(FH[0][1]), "+v"(FH[0][2]), "+v"(FH[0][3]),     \
          "+v"(FH[1][0]), "+v"(FH[1][1]), "+v"(FH[1][2]), "+v"(FH[1][3]),     \
          "+v"(FL[0][0]), "+v"(FL[0][1]), "+v"(FL[0][2]), "+v"(FL[0][3]),     \
          "+v"(FL[1][0]), "+v"(FL[1][1]), "+v"(FL[1][2]), "+v"(FL[1][3])      \
        :: "memory")

// x -> split planes, layout [t][k>>3][b][k&7] u16 per plane
__global__ void __launch_bounds__(256)
transpose_pack_x(const float* __restrict__ x,
                 unsigned short* __restrict__ xH, unsigned short* __restrict__ xL)
{
    __shared__ float tile[64][65];
    const int t   = (int)blockIdx.x;
    const int tid = (int)threadIdx.x;
    const int li  = tid & 63;
    const int w4  = tid >> 6;

    for (int kc = 0; kc < II; kc += 64) {
#pragma unroll
        for (int r = 0; r < 16; ++r) {
            const int b = w4 * 16 + r;
            tile[b][li] = x[((size_t)b * TT + t) * II + kc + li];
        }
        __syncthreads();
#pragma unroll
        for (int half = 0; half < 2; ++half) {
            const int u  = tid + half * 256;      // u = k8*64 + b
            const int k8 = u >> 6, b = u & 63;
            unsigned short oh[8], ol[8];
#pragma unroll
            for (int e = 0; e < 8; ++e) {
                unsigned hi, lo;
                split_bf16(tile[b][k8 * 8 + e], hi, lo);
                oh[e] = (unsigned short)hi;
                ol[e] = (unsigned short)lo;
            }
            const size_t idx = (size_t)t * XT_STRIDE + ((kc >> 3) + k8) * 512 + b * 8;
            *(uint4*)(xH + idx) = *(const uint4*)oh;
            *(uint4*)(xL + idx) = *(const uint4*)ol;
        }
        __syncthreads();
    }
}

__global__ void __launch_bounds__(NTHR, 2)   // <=256 VGPR, 1 block/CU
lstm_mfma(const unsigned short* __restrict__ xH,
          const unsigned short* __restrict__ xL,
          const int*   __restrict__ lens,
          const float* __restrict__ Wih,     // [4H][I]
          const float* __restrict__ Whh,     // [4H][H]
          const float* __restrict__ bih,
          const float* __restrict__ bhh,
          unsigned short* __restrict__ hH,   // [2][H/8][B][8]
          unsigned short* __restrict__ hL,
          int*   __restrict__ cnts,          // 8 counters, 64-int stride
          float* __restrict__ out)           // [B][H]
{
    __shared__ float red[2][2][3][2][16][17];     // ~26KB
    __shared__ unsigned short hstg[2][128][256];  // [plane][chunk][b*8] 128KB
    __shared__ int hflag;                         // step-ready broadcast

    const int tid  = (int)threadIdx.x;
    const int l    = tid & 63;
    const int p    = __builtin_amdgcn_readfirstlane(tid >> 6);  // wave 0..7
    const int kh   = p & 3;                  // k-split 0..3
    const int mt   = p >> 2;                 // m-tile 0..1
    const int bsub = l & 15;
    const int q    = l >> 4;                 // quad

    const int jt = (int)blockIdx.x >> 1;
    const int bh = (int)blockIdx.x & 1;
    const int j0 = jt * 8;

    const int bofs[2] = {(bh * 32 + bsub) * 8, (bh * 32 + 16 + bsub) * 8};

    int*       prodc = cnts + (bh * 4 + (jt >> 5)) * 64;   // my quarter's counter
    const int* pollc = cnts + (bh * 4 + (l & 3)) * 64;     // poller: lane l&3's quarter

    // ---- weight A-fragments -> registers (persist across all t) ----
    const int row = (l & 3) * HH + j0 + mt * 4 + ((l & 15) >> 2);
    bf16x8 whi[12], wlo[12];
#pragma unroll
    for (int kt = 0; kt < 12; ++kt) {
        const int ktg = (kt < 4) ? (4 * kh + kt) : (16 + 8 * kh + (kt - 4));
        const float* src = (ktg < 16)
            ? (Wih + (size_t)row * II + ktg * 32 + q * 8)
            : (Whh + (size_t)row * HH + (ktg - 16) * 32 + q * 8);
        const float4 w0 = *(const float4*)src;
        const float4 w1 = *(const float4*)(src + 4);
        const float wf[8] = {w0.x, w0.y, w0.z, w0.w, w1.x, w1.y, w1.z, w1.w};
#pragma unroll
        for (int e = 0; e < 8; ++e) {
            unsigned hi, lo;
            split_bf16(wf[e], hi, lo);
            whi[kt][e] = (short)hi;
            wlo[kt][e] = (short)lo;
        }
    }

    // ---- per-cell state; init h_0, ack, publish ----
    float bias[4], c[2] = {0.f, 0.f}, lasth[2] = {0.f, 0.f};
    int len[2] = {0, 0};
    const int jcell = j0 + mt * 4 + q;
    const int jlow  = mt * 4 + q;
    const size_t hblk = (size_t)jt * 512;

    if (kh == 0) {
#pragma unroll
        for (int g = 0; g < 4; ++g)
            bias[g] = bih[g * HH + jcell] + bhh[g * HH + jcell];
#pragma unroll
        for (int nt = 0; nt < 2; ++nt) {
            const int b = bh * 32 + nt * 16 + bsub;
            len[nt] = lens[b];
            store_wt_u16(hH + hblk + b * 8 + jlow, 0);   // h_0 = 0, buffer 0
            store_wt_u16(hL + hblk + b * 8 + jlow, 0);
        }
        asm volatile("s_waitcnt vmcnt(0)" ::: "memory");
        if (l == 0) atomic_add_rlx(prodc);               // -> 64 when all ready
    }

    // ---- flag init before any poll ----
    if (tid == 0)
        __hip_atomic_store(&hflag, 0, __ATOMIC_RELAXED, __HIP_MEMORY_SCOPE_WORKGROUP);
    __syncthreads();

    for (int t = 0; t < TT; ++t) {
        // ---- x-part (plain cached b128 loads; independent of h_t) ----
        f32x4 s0[2], s1[2], s2[2];
#pragma unroll
        for (int nt = 0; nt < 2; ++nt)
            s0[nt] = s1[nt] = s2[nt] = (f32x4){0.f, 0.f, 0.f, 0.f};
        {
            const unsigned short* xh = xH + (size_t)t * XT_STRIDE;
            const unsigned short* xl = xL + (size_t)t * XT_STRIDE;
#pragma unroll
            for (int xi = 0; xi < 4; ++xi) {
                const int idx = ((4 * kh + xi) * 4 + q) * 512;
#pragma unroll
                for (int nt = 0; nt < 2; ++nt) {
                    const bf16x8 ahi = *(const bf16x8*)(xh + idx + bofs[nt]);
                    const bf16x8 alo = *(const bf16x8*)(xl + idx + bofs[nt]);
                    s0[nt] = MFMA(whi[xi], ahi, s0[nt]);
                    s1[nt] = MFMA(whi[xi], alo, s1[nt]);
                    s2[nt] = MFMA(wlo[xi], ahi, s2[nt]);
                }
            }
        }

        // ---- step-ready: wave 7 polls LLC counters, others spin on LDS ----
        {
            const int need = 64 * (t + 1);
            if (p == 7) {
                while (load_rlx(pollc) < need)       // divergent: exits when all
                    __builtin_amdgcn_s_sleep(1);     // 4 quarters (l&3) pass
                if (l == 0)
                    __hip_atomic_store(&hflag, t + 1, __ATOMIC_RELAXED,
                                       __HIP_MEMORY_SCOPE_WORKGROUP);
            } else {
                while (__hip_atomic_load(&hflag, __ATOMIC_RELAXED,
                                         __HIP_MEMORY_SCOPE_WORKGROUP) < t + 1)
                    __builtin_amdgcn_s_sleep(1);
            }
            asm volatile("" ::: "memory");
        }

        // ---- h-part stage: each wave coherently loads its mt-half only ----
        const unsigned short* hph = hH + (t & 1) * HBUF_STRIDE;
        const unsigned short* hpl = hL + (t & 1) * HBUF_STRIDE;
        {
            u32x4 fh[2][4], fl[2][4];
#pragma unroll
            for (int nt = 0; nt < 2; ++nt)
#pragma unroll
                for (int r = 0; r < 4; ++r) {
                    const int hi2 = mt * 4 + r;
                    const int idx = (kh * 32 + hi2 * 4 + q) * 512 + bofs[nt];
                    issue_coh(hph + idx, fh[nt][r]);
                    issue_coh(hpl + idx, fl[nt][r]);
                }
            WAITSTG(fh, fl);
#pragma unroll
            for (int nt = 0; nt < 2; ++nt)
#pragma unroll
                for (int r = 0; r < 4; ++r) {
                    const int cc = kh * 32 + (mt * 4 + r) * 4 + q;
                    const int lo = (nt * 16 + bsub) * 8;
                    *(u32x4*)&hstg[0][cc][lo] = fh[nt][r];
                    *(u32x4*)&hstg[1][cc][lo] = fl[nt][r];
                }
        }
        __syncthreads();

        // ---- h-part consume: all 8 hi2 fragments from LDS ----
#pragma unroll
        for (int nt = 0; nt < 2; ++nt) {
#pragma unroll
            for (int hi2 = 0; hi2 < 8; ++hi2) {
                const int cc = kh * 32 + hi2 * 4 + q;
                const int lo = (nt * 16 + bsub) * 8;
                const bf16x8 ahi = *(const bf16x8*)&hstg[0][cc][lo];
                const bf16x8 alo = *(const bf16x8*)&hstg[1][cc][lo];
                s0[nt] = MFMA(whi[4 + hi2], ahi, s0[nt]);
                s1[nt] = MFMA(whi[4 + hi2], alo, s1[nt]);
                s2[nt] = MFMA(wlo[4 + hi2], ahi, s2[nt]);
            }
        }

        // ---- merge streams + single-phase cross-wave reduction ----
        f32x4 acc[2];
#pragma unroll
        for (int nt = 0; nt < 2; ++nt) acc[nt] = s0[nt] + s1[nt] + s2[nt];
        const int pa = t & 1;

        if (kh != 0) {
#pragma unroll
            for (int nt = 0; nt < 2; ++nt)
#pragma unroll
                for (int i = 0; i < 4; ++i)
                    red[pa][mt][kh - 1][nt][bsub][4 * q + i] = acc[nt][i];
        }
        __syncthreads();

        // ---- gate math (kh==0), h store, ack, publish ----
        if (kh == 0) {
            unsigned short* dsth = hH + ((t + 1) & 1) * HBUF_STRIDE + hblk;
            unsigned short* dstl = hL + ((t + 1) & 1) * HBUF_STRIDE + hblk;
#pragma unroll
            for (int nt = 0; nt < 2; ++nt) {
                float g4[4];
#pragma unroll
                for (int i = 0; i < 4; ++i)
                    g4[i] = acc[nt][i] + bias[i]
                          + red[pa][mt][0][nt][bsub][4 * q + i]
                          + red[pa][mt][1][nt][bsub][4 * q + i]
                          + red[pa][mt][2][nt][bsub][4 * q + i];
                const float ig = fast_sigmoid(g4[0]);
                const float fg = fast_sigmoid(g4[1]);
                const float gg = fast_tanh(g4[2]);
                const float og = fast_sigmoid(g4[3]);
                c[nt] = fg * c[nt] + ig * gg;
                const float h = og * fast_tanh(c[nt]);
                unsigned hi, lo;
                split_bf16(h, hi, lo);
                const int b = bh * 32 + nt * 16 + bsub;
                store_wt_u16(dsth + b * 8 + jlow, (unsigned short)hi);
                store_wt_u16(dstl + b * 8 + jlow, (unsigned short)lo);
                if (t == len[nt] - 1) lasth[nt] = h;
            }
            asm volatile("s_waitcnt vmcnt(0)" ::: "memory");  // h stores visible
            if (l == 0) atomic_add_rlx(prodc);                // publish h_{t+1}
        }
    }

    // ---- epilogue ----
    if (kh == 0) {
#pragma unroll
        for (int nt = 0; nt < 2; ++nt) {
            const int b = bh * 32 + nt * 16 + bsub;
            out[(size_t)b * HH + jcell] = lasth[nt];
        }
    }
}

extern "C" void kernel_launch(void* const* d_in, const int* in_sizes, int n_in,
                              void* d_out, int out_size, void* d_ws, size_t ws_size,
                              hipStream_t stream)
{
    const float* seq  = (const float*)d_in[0];
    const int*   lens = (const int*)  d_in[1];
    const float* Wih  = (const float*)d_in[2];
    const float* Whh  = (const float*)d_in[3];
    const float* bih  = (const float*)d_in[4];
    const float* bhh  = (const float*)d_in[5];
    float* out = (float*)d_out;

    char* ws = (char*)d_ws;
    int*            cnts = (int*)           (ws + WS_CNT_OFF);
    unsigned short* hH   = (unsigned short*)(ws + WS_HPAKH_OFF);
    unsigned short* hL   = (unsigned short*)(ws + WS_HPAKL_OFF);
    unsigned short* xH   = (unsigned short*)(ws + WS_XPAKH_OFF);
    unsigned short* xL   = (unsigned short*)(ws + WS_XPAKL_OFF);

    hipMemsetAsync(cnts, 0, 8192, stream);   // monotonic counters start at 0
    transpose_pack_x<<<dim3(TT), dim3(256), 0, stream>>>(seq, xH, xL);
    lstm_mfma<<<dim3(NBLK), dim3(NTHR), 0, stream>>>(xH, xL, lens, Wih, Whh, bih, bhh,
                                                     hH, hL, cnts, out);
}

// Round 6
// 2460.532 us; speedup vs baseline: 4.4189x; 1.1186x over previous
//
#include <hip/hip_runtime.h>

// LSTM B=64 T=512 I=512 H=1024 — round 13.
// R12 (single poller): neutral => poll contention exonerated. Remaining model:
// step = fixed latency chain (~2us) + LLC service term on 32 MB/step coherent
// h reads. RE-TILE: blocks (128 jt x 2 bh) -> (64 jt x 4 bq): j_slice 16,
// b_slice 16. Coherent h traffic = 256 blocks x 1024ch x b_slice x 4B depends
// only on b_slice => 32 -> 16 MB/step; load burst/wave 16->8 b128; x burst
// halves; counter need 64->32. MFMA/wave unchanged (M=64 rows: each wave owns
// 2 m-tiles u in {0,1}; j = j0 + (mt*2+u)*4 + q). VGPR squeeze for the 2x
// A-frags (192 regs): s1/s2 streams merged into one acc s12 (sum order only),
// bias in LDS table (256B), stage temps 8x u32x4. Sync protocol identical:
// 16 counters (bq x quarter), 16 producer blocks x 2 waves = need 32*(t+1);
// D=2 buffer overwrite safety argument carries (publish of h_{t+2} data-deps
// on detect of h_{t+1} which data-deps on every block's completed h_t loads).

typedef short bf16x8 __attribute__((ext_vector_type(8)));
typedef float f32x4  __attribute__((ext_vector_type(4)));
typedef unsigned u32x4 __attribute__((ext_vector_type(4)));

#define BB 64
#define TT 512
#define II 512
#define HH 1024

#define NBLK 256
#define NTHR 512

// ws layout (bytes)
#define WS_CNT_OFF   0                       // 16 counters, 256B apart (memset 8K)
#define WS_HPAKH_OFF 8192                    // u16 [2][HH/8][BB][8] = 256 KB
#define WS_HPAKL_OFF (8192 + 262144)
#define WS_XPAKH_OFF (1 << 20)               // u16 [TT][II/8][BB][8] = 32 MB
#define WS_XPAKL_OFF ((1 << 20) + (32u << 20))

#define HBUF_STRIDE 65536                    // u16 per h buffer
#define XT_STRIDE   32768                    // u16 per timestep of x

__device__ __forceinline__ int atomic_add_rlx(int* p) {
    return __hip_atomic_fetch_add(p, 1, __ATOMIC_RELAXED, __HIP_MEMORY_SCOPE_AGENT);
}
__device__ __forceinline__ int load_rlx(const int* p) {
    return __hip_atomic_load(p, __ATOMIC_RELAXED, __HIP_MEMORY_SCOPE_AGENT);
}
__device__ __forceinline__ void store_wt_u16(unsigned short* p, unsigned short v) {
    __hip_atomic_store(p, v, __ATOMIC_RELAXED, __HIP_MEMORY_SCOPE_AGENT);
}

__device__ __forceinline__ float fast_sigmoid(float x) {
    return 1.0f / (1.0f + __expf(-x));
}
__device__ __forceinline__ float fast_tanh(float x) {
    x = fminf(15.0f, fmaxf(-15.0f, x));
    const float e = __expf(2.0f * x);
    return (e - 1.0f) / (e + 1.0f);
}

// fp32 -> bf16 hi + bf16 lo-of-residual (RNE both)
__device__ __forceinline__ void split_bf16(float x, unsigned& hi, unsigned& lo)
{
    unsigned b = __float_as_uint(x);
    hi = (b + 0x7fffu + ((b >> 16) & 1u)) >> 16;
    float r = x - __uint_as_float(hi << 16);
    unsigned bl = __float_as_uint(r);
    lo = (bl + 0x7fffu + ((bl >> 16) & 1u)) >> 16;
}

#define MFMA(A, B, C) __builtin_amdgcn_mfma_f32_16x16x32_bf16((A), (B), (C), 0, 0, 0)

// coherent 16B load, issued WITHOUT wait (MUST pair with WAITSTG8 below)
__device__ __forceinline__ void issue_coh(const unsigned short* p, u32x4& d)
{
    asm volatile("global_load_dwordx4 %0, %1, off sc0 sc1" : "=v"(d) : "v"(p));
}
// drain all VMEM; loaded values flow THROUGH the wait so uses can't be hoisted
#define WAITSTG8(FH, FL)                                                      \
    asm volatile("s_waitcnt vmcnt(0)"                                         \
        : "+v"(FH[0]), "+v"(FH[1]), "+v"(FH[2]), "+v"(FH[3]),                 \
          "+v"(FL[0]), "+v"(FL[1]), "+v"(FL[2]), "+v"(FL[3])                  \
        :: "memory")

// x -> split planes, layout [t][k>>3][b][k&7] u16 per plane
__global__ void __launch_bounds__(256)
transpose_pack_x(const float* __restrict__ x,
                 unsigned short* __restrict__ xH, unsigned short* __restrict__ xL)
{
    __shared__ float tile[64][65];
    const int t   = (int)blockIdx.x;
    const int tid = (int)threadIdx.x;
    const int li  = tid & 63;
    const int w4  = tid >> 6;

    for (int kc = 0; kc < II; kc += 64) {
#pragma unroll
        for (int r = 0; r < 16; ++r) {
            const int b = w4 * 16 + r;
            tile[b][li] = x[((size_t)b * TT + t) * II + kc + li];
        }
        __syncthreads();
#pragma unroll
        for (int half = 0; half < 2; ++half) {
            const int u  = tid + half * 256;      // u = k8*64 + b
            const int k8 = u >> 6, b = u & 63;
            unsigned short oh[8], ol[8];
#pragma unroll
            for (int e = 0; e < 8; ++e) {
                unsigned hi, lo;
                split_bf16(tile[b][k8 * 8 + e], hi, lo);
                oh[e] = (unsigned short)hi;
                ol[e] = (unsigned short)lo;
            }
            const size_t idx = (size_t)t * XT_STRIDE + ((kc >> 3) + k8) * 512 + b * 8;
            *(uint4*)(xH + idx) = *(const uint4*)oh;
            *(uint4*)(xL + idx) = *(const uint4*)ol;
        }
        __syncthreads();
    }
}

__global__ void __launch_bounds__(NTHR, 2)   // <=256 VGPR, 1 block/CU
lstm_mfma(const unsigned short* __restrict__ xH,
          const unsigned short* __restrict__ xL,
          const int*   __restrict__ lens,
          const float* __restrict__ Wih,     // [4H][I]
          const float* __restrict__ Whh,     // [4H][H]
          const float* __restrict__ bih,
          const float* __restrict__ bhh,
          unsigned short* __restrict__ hH,   // [2][H/8][B][8]
          unsigned short* __restrict__ hL,
          int*   __restrict__ cnts,          // 16 counters, 64-int stride
          float* __restrict__ out)           // [B][H]
{
    __shared__ float red[2][2][3][2][16][17];     // [pa][mt][kh-1][u][bsub][17] ~26KB
    __shared__ unsigned short hstg[2][128][128];  // [plane][chunk][b16*8] 64KB
    __shared__ float biaslds[4][16];              // [gate][j-within-block]
    __shared__ int hflag;                         // step-ready broadcast

    const int tid  = (int)threadIdx.x;
    const int l    = tid & 63;
    const int p    = __builtin_amdgcn_readfirstlane(tid >> 6);  // wave 0..7
    const int kh   = p & 3;                  // k-split 0..3
    const int mt   = p >> 2;                 // m-pair 0..1 (tiles mt*2+u)
    const int bsub = l & 15;
    const int q    = l >> 4;                 // quad

    const int jt = (int)blockIdx.x >> 2;     // 0..63  (16 channels each)
    const int bq = (int)blockIdx.x & 3;      // 0..3   (16 batch each)
    const int j0 = jt * 16;
    const int b0 = bq * 16;

    const int bofs = (b0 + bsub) * 8;        // u16 offset of my batch lane

    int*       prodc = cnts + (bq * 4 + (jt >> 4)) * 64;  // my quarter's counter
    const int* pollc = cnts + (bq * 4 + (l & 3)) * 64;    // poller: lane l&3's quarter

    // ---- weight A-fragments -> registers (persist across all t) ----
    bf16x8 whi[2][12], wlo[2][12];
#pragma unroll
    for (int u = 0; u < 2; ++u) {
        const int row = (l & 3) * HH + j0 + (mt * 2 + u) * 4 + ((l & 15) >> 2);
#pragma unroll
        for (int kt = 0; kt < 12; ++kt) {
            const int ktg = (kt < 4) ? (4 * kh + kt) : (16 + 8 * kh + (kt - 4));
            const float* src = (ktg < 16)
                ? (Wih + (size_t)row * II + ktg * 32 + q * 8)
                : (Whh + (size_t)row * HH + (ktg - 16) * 32 + q * 8);
            const float4 w0 = *(const float4*)src;
            const float4 w1 = *(const float4*)(src + 4);
            const float wf[8] = {w0.x, w0.y, w0.z, w0.w, w1.x, w1.y, w1.z, w1.w};
#pragma unroll
            for (int e = 0; e < 8; ++e) {
                unsigned hi, lo;
                split_bf16(wf[e], hi, lo);
                whi[u][kt][e] = (short)hi;
                wlo[u][kt][e] = (short)lo;
            }
        }
    }

    // ---- per-cell state; init h_0, ack, publish ----
    float c[2] = {0.f, 0.f}, lasth[2] = {0.f, 0.f};
    int len = 0;
    const size_t hchunk = (size_t)(2 * jt + mt) * 512;  // my output chunk row

    if (kh == 0) {
        len = lens[b0 + bsub];
#pragma unroll
        for (int u = 0; u < 2; ++u) {
            store_wt_u16(hH + hchunk + bofs + 4 * u + q, 0);   // h_0 = 0, buffer 0
            store_wt_u16(hL + hchunk + bofs + 4 * u + q, 0);
        }
        asm volatile("s_waitcnt vmcnt(0)" ::: "memory");
        if (l == 0) atomic_add_rlx(prodc);               // -> 32 when all ready
    }

    // ---- bias table + flag init before any poll ----
    if (tid < 64) {
        const int gi = tid >> 4, jj = tid & 15;
        biaslds[gi][jj] = bih[gi * HH + j0 + jj] + bhh[gi * HH + j0 + jj];
    }
    if (tid == 0)
        __hip_atomic_store(&hflag, 0, __ATOMIC_RELAXED, __HIP_MEMORY_SCOPE_WORKGROUP);
    __syncthreads();

    for (int t = 0; t < TT; ++t) {
        // ---- x-part (plain cached b128 loads; independent of h_t) ----
        f32x4 s0[2], s12[2];
#pragma unroll
        for (int u = 0; u < 2; ++u)
            s0[u] = s12[u] = (f32x4){0.f, 0.f, 0.f, 0.f};
        {
            const unsigned short* xh = xH + (size_t)t * XT_STRIDE;
            const unsigned short* xl = xL + (size_t)t * XT_STRIDE;
#pragma unroll
            for (int xi = 0; xi < 4; ++xi) {
                const int idx = ((4 * kh + xi) * 4 + q) * 512 + bofs;
                const bf16x8 ahi = *(const bf16x8*)(xh + idx);
                const bf16x8 alo = *(const bf16x8*)(xl + idx);
#pragma unroll
                for (int u = 0; u < 2; ++u) {
                    s0[u]  = MFMA(whi[u][xi], ahi, s0[u]);
                    s12[u] = MFMA(whi[u][xi], alo, s12[u]);
                    s12[u] = MFMA(wlo[u][xi], ahi, s12[u]);
                }
            }
        }

        // ---- step-ready: wave 7 polls LLC counters, others spin on LDS ----
        {
            const int need = 32 * (t + 1);
            if (p == 7) {
                while (load_rlx(pollc) < need)       // divergent: exits when all
                    __builtin_amdgcn_s_sleep(1);     // 4 quarters (l&3) pass
                if (l == 0)
                    __hip_atomic_store(&hflag, t + 1, __ATOMIC_RELAXED,
                                       __HIP_MEMORY_SCOPE_WORKGROUP);
            } else {
                while (__hip_atomic_load(&hflag, __ATOMIC_RELAXED,
                                         __HIP_MEMORY_SCOPE_WORKGROUP) < t + 1)
                    __builtin_amdgcn_s_sleep(1);
            }
            asm volatile("" ::: "memory");
        }

        // ---- h-part stage: each wave coherently loads its 16 chunks ----
        const unsigned short* hph = hH + (t & 1) * HBUF_STRIDE;
        const unsigned short* hpl = hL + (t & 1) * HBUF_STRIDE;
        {
            u32x4 fh[4], fl[4];
#pragma unroll
            for (int r = 0; r < 4; ++r) {
                const int chunk = kh * 32 + mt * 16 + r * 4 + q;
                const int idx = chunk * 512 + bofs;
                issue_coh(hph + idx, fh[r]);
                issue_coh(hpl + idx, fl[r]);
            }
            WAITSTG8(fh, fl);
#pragma unroll
            for (int r = 0; r < 4; ++r) {
                const int chunk = kh * 32 + mt * 16 + r * 4 + q;
                *(u32x4*)&hstg[0][chunk][bsub * 8] = fh[r];
                *(u32x4*)&hstg[1][chunk][bsub * 8] = fl[r];
            }
        }
        __syncthreads();

        // ---- h-part consume: 8 k-steps of my quarter from LDS ----
#pragma unroll
        for (int hi2 = 0; hi2 < 8; ++hi2) {
            const int chunk = kh * 32 + hi2 * 4 + q;
            const bf16x8 ahi = *(const bf16x8*)&hstg[0][chunk][bsub * 8];
            const bf16x8 alo = *(const bf16x8*)&hstg[1][chunk][bsub * 8];
#pragma unroll
            for (int u = 0; u < 2; ++u) {
                s0[u]  = MFMA(whi[u][4 + hi2], ahi, s0[u]);
                s12[u] = MFMA(whi[u][4 + hi2], alo, s12[u]);
                s12[u] = MFMA(wlo[u][4 + hi2], ahi, s12[u]);
            }
        }

        // ---- merge streams + single-phase cross-wave reduction ----
        f32x4 acc[2];
#pragma unroll
        for (int u = 0; u < 2; ++u) acc[u] = s0[u] + s12[u];
        const int pa = t & 1;

        if (kh != 0) {
#pragma unroll
            for (int u = 0; u < 2; ++u)
#pragma unroll
                for (int i = 0; i < 4; ++i)
                    red[pa][mt][kh - 1][u][bsub][4 * q + i] = acc[u][i];
        }
        __syncthreads();

        // ---- gate math (kh==0), h store, ack, publish ----
        if (kh == 0) {
            unsigned short* dsth = hH + ((t + 1) & 1) * HBUF_STRIDE + hchunk;
            unsigned short* dstl = hL + ((t + 1) & 1) * HBUF_STRIDE + hchunk;
#pragma unroll
            for (int u = 0; u < 2; ++u) {
                const int jj = (mt * 2 + u) * 4 + q;
                float g4[4];
#pragma unroll
                for (int i = 0; i < 4; ++i)
                    g4[i] = acc[u][i] + biaslds[i][jj]
                          + red[pa][mt][0][u][bsub][4 * q + i]
                          + red[pa][mt][1][u][bsub][4 * q + i]
                          + red[pa][mt][2][u][bsub][4 * q + i];
                const float ig = fast_sigmoid(g4[0]);
                const float fg = fast_sigmoid(g4[1]);
                const float gg = fast_tanh(g4[2]);
                const float og = fast_sigmoid(g4[3]);
                c[u] = fg * c[u] + ig * gg;
                const float h = og * fast_tanh(c[u]);
                unsigned hi, lo;
                split_bf16(h, hi, lo);
                store_wt_u16(dsth + bofs + 4 * u + q, (unsigned short)hi);
                store_wt_u16(dstl + bofs + 4 * u + q, (unsigned short)lo);
                if (t == len - 1) lasth[u] = h;
            }
            asm volatile("s_waitcnt vmcnt(0)" ::: "memory");  // h stores visible
            if (l == 0) atomic_add_rlx(prodc);                // publish h_{t+1}
        }
    }

    // ---- epilogue ----
    if (kh == 0) {
#pragma unroll
        for (int u = 0; u < 2; ++u) {
            const int jj = (mt * 2 + u) * 4 + q;
            out[(size_t)(b0 + bsub) * HH + j0 + jj] = lasth[u];
        }
    }
}

extern "C" void kernel_launch(void* const* d_in, const int* in_sizes, int n_in,
                              void* d_out, int out_size, void* d_ws, size_t ws_size,
                              hipStream_t stream)
{
    const float* seq  = (const float*)d_in[0];
    const int*   lens = (const int*)  d_in[1];
    const float* Wih  = (const float*)d_in[2];
    const float* Whh  = (const float*)d_in[3];
    const float* bih  = (const float*)d_in[4];
    const float* bhh  = (const float*)d_in[5];
    float* out = (float*)d_out;

    char* ws = (char*)d_ws;
    int*            cnts = (int*)           (ws + WS_CNT_OFF);
    unsigned short* hH   = (unsigned short*)(ws + WS_HPAKH_OFF);
    unsigned short* hL   = (unsigned short*)(ws + WS_HPAKL_OFF);
    unsigned short* xH   = (unsigned short*)(ws + WS_XPAKH_OFF);
    unsigned short* xL   = (unsigned short*)(ws + WS_XPAKL_OFF);

    hipMemsetAsync(cnts, 0, 8192, stream);   // monotonic counters start at 0
    transpose_pack_x<<<dim3(TT), dim3(256), 0, stream>>>(seq, xH, xL);
    lstm_mfma<<<dim3(NBLK), dim3(NTHR), 0, stream>>>(xH, xL, lens, Wih, Whh, bih, bhh,
                                                     hH, hL, cnts, out);
}